// Round 1
// baseline (394.976 us; speedup 1.0000x reference)
//
#include <hip/hip_runtime.h>
#include <hip/hip_bf16.h>
#include <math.h>

#define H 256
#define F 512
#define E 8
#define T_TOK 32768
#define BM 128   // tokens per block
#define FC 64    // F-chunk size

typedef float    f32x4 __attribute__((__ext_vector_type__(4)));
typedef _Float16 f16x8 __attribute__((__ext_vector_type__(8)));
typedef _Float16 f16x4 __attribute__((__ext_vector_type__(4)));

__device__ __forceinline__ float gelu_exact(float v) {
    return 0.5f * v * (1.0f + erff(v * 0.70710678118654752f));
}

// ---- transpose + convert: per expert, in fp32 [R][C] -> out fp16 [C][R]
__global__ void transpose_cvt(const float* __restrict__ in, _Float16* __restrict__ out,
                              int R, int C) {
    __shared__ float tile[32][33];
    int e = blockIdx.z;
    const float* inp = in + (size_t)e * R * C;
    _Float16* outp = out + (size_t)e * R * C;
    int c0 = blockIdx.x * 32, r0 = blockIdx.y * 32;
    int tx = threadIdx.x, ty = threadIdx.y; // 32 x 8
    for (int i = 0; i < 32; i += 8)
        tile[ty + i][tx] = inp[(size_t)(r0 + ty + i) * C + c0 + tx];
    __syncthreads();
    for (int i = 0; i < 32; i += 8)
        outp[(size_t)(c0 + ty + i) * R + r0 + tx] = (_Float16)tile[tx][ty + i];
}

// ---- gate: probs = softmax(x @ Wg + bg) over E; 8 threads per token
__global__ void gate_kernel(const float* __restrict__ x, const float* __restrict__ Wg,
                            const float* __restrict__ bg, float* __restrict__ probs) {
    int gid = blockIdx.x * blockDim.x + threadIdx.x;
    int t = gid >> 3, e = gid & 7;
    const float* xr = x + (size_t)t * H;
    float acc = 0.f;
    for (int k = 0; k < H; k += 4) {
        float4 xv = *(const float4*)(xr + k);
        acc += xv.x * Wg[(k + 0) * E + e] + xv.y * Wg[(k + 1) * E + e]
             + xv.z * Wg[(k + 2) * E + e] + xv.w * Wg[(k + 3) * E + e];
    }
    acc += bg[e];
    float m = acc;
    for (int s = 1; s < 8; s <<= 1) m = fmaxf(m, __shfl_xor(m, s, 8));
    float p = expf(acc - m);
    float sum = p;
    for (int s = 1; s < 8; s <<= 1) sum += __shfl_xor(sum, s, 8);
    probs[gid] = p / sum;
}

// ---- main fused MoE FFN
__global__ __launch_bounds__(512) void moe_main(
    const float* __restrict__ x, const _Float16* __restrict__ W1t,
    const float* __restrict__ b1, const _Float16* __restrict__ W2t,
    const float* __restrict__ b2, const float* __restrict__ probs,
    float* __restrict__ out) {

    __shared__ __align__(16) _Float16 xs[BM * H];   // 64 KB  (token-major, swizzled)
    __shared__ __align__(16) _Float16 w1s[FC * H];  // 32 KB  (f-major, K=H contiguous)
    __shared__ __align__(16) _Float16 w2s[H * FC];  // 32 KB  (h-major, K=f contiguous)
    __shared__ __align__(16) _Float16 hs[BM * FC];  // 16 KB  (token-major, K=f contiguous)

    int tid = threadIdx.x;
    int lane = tid & 63, wid = tid >> 6;
    int t0 = blockIdx.x * BM;
    int l15 = lane & 15, l4 = lane >> 4;

    // stage x -> fp16 LDS (reused by all 8 experts)
    for (int i = tid; i < BM * H / 8; i += 512) {
        int r = i >> 5;             // 32 chunks of 8 per row
        int c8 = (i & 31) << 3;
        const float4* gp = (const float4*)(x + (size_t)(t0 + r) * H + c8);
        float4 v0 = gp[0], v1 = gp[1];
        f16x8 hv;
        hv[0] = (_Float16)v0.x; hv[1] = (_Float16)v0.y; hv[2] = (_Float16)v0.z; hv[3] = (_Float16)v0.w;
        hv[4] = (_Float16)v1.x; hv[5] = (_Float16)v1.y; hv[6] = (_Float16)v1.z; hv[7] = (_Float16)v1.w;
        int idx = (r * H + c8) ^ ((r & 7) << 3);
        *(f16x8*)&xs[idx] = hv;
    }

    // wave coords
    int fw = wid >> 2, tw1 = wid & 3;   // GEMM1: 2(f) x 4(tok) wave grid, 2x2 tiles each
    int hw = wid >> 1, tw2 = wid & 1;   // GEMM2: 4(h) x 2(tok) wave grid, 4x4 tiles each

    f32x4 mix[4][4];
    for (int i = 0; i < 4; ++i)
        for (int j = 0; j < 4; ++j) mix[i][j] = (f32x4){0.f, 0.f, 0.f, 0.f};

    for (int e = 0; e < E; ++e) {
        const _Float16* W1e = W1t + (size_t)e * F * H;
        const _Float16* W2e = W2t + (size_t)e * H * F;
        f32x4 yacc[4][4];
        for (int i = 0; i < 4; ++i)
            for (int j = 0; j < 4; ++j) yacc[i][j] = (f32x4){0.f, 0.f, 0.f, 0.f};

        for (int c = 0; c < F / FC; ++c) {
            int fbase = c * FC;
            __syncthreads();   // prev chunk's reads done before overwriting LDS

            // stage W1t chunk: rows f=0..FC-1, K=H (fully contiguous 32 KB)
            for (int i = tid; i < FC * H / 8; i += 512) {
                int r = i >> 5, c8 = (i & 31) << 3;
                f16x8 v = *(const f16x8*)(W1e + (size_t)(fbase + r) * H + c8);
                int idx = (r * H + c8) ^ ((r & 7) << 3);
                *(f16x8*)&w1s[idx] = v;
            }
            // stage W2t chunk: rows h=0..255, K = f in [fbase, fbase+FC)
            for (int i = tid; i < H * FC / 8; i += 512) {
                int r = i >> 3, c8 = (i & 7) << 3;
                f16x8 v = *(const f16x8*)(W2e + (size_t)r * F + fbase + c8);
                int idx = (r * FC + c8) ^ ((r & 7) << 3);
                *(f16x8*)&w2s[idx] = v;
            }
            __syncthreads();

            // GEMM1: hT[f_chunk][tok] = W1t_chunk · x^T  (2x2 tiles/wave, K=H)
            f32x4 hacc[2][2];
            hacc[0][0] = hacc[0][1] = hacc[1][0] = hacc[1][1] = (f32x4){0.f, 0.f, 0.f, 0.f};
            for (int ks = 0; ks < H / 32; ++ks) {
                int kidx = ks * 32 + (l4 << 3);
                int fr0 = (fw * 2) * 16 + l15, fr1 = fr0 + 16;
                int tr0 = (tw1 * 2) * 16 + l15, tr1 = tr0 + 16;
                f16x8 a0 = *(const f16x8*)&w1s[(fr0 * H + kidx) ^ ((fr0 & 7) << 3)];
                f16x8 a1 = *(const f16x8*)&w1s[(fr1 * H + kidx) ^ ((fr1 & 7) << 3)];
                f16x8 b0 = *(const f16x8*)&xs[(tr0 * H + kidx) ^ ((tr0 & 7) << 3)];
                f16x8 b1v = *(const f16x8*)&xs[(tr1 * H + kidx) ^ ((tr1 & 7) << 3)];
                hacc[0][0] = __builtin_amdgcn_mfma_f32_16x16x32_f16(a0, b0, hacc[0][0], 0, 0, 0);
                hacc[0][1] = __builtin_amdgcn_mfma_f32_16x16x32_f16(a0, b1v, hacc[0][1], 0, 0, 0);
                hacc[1][0] = __builtin_amdgcn_mfma_f32_16x16x32_f16(a1, b0, hacc[1][0], 0, 0, 0);
                hacc[1][1] = __builtin_amdgcn_mfma_f32_16x16x32_f16(a1, b1v, hacc[1][1], 0, 0, 0);
            }
            // epilogue: + b1, GELU(erf), fp16, pack 4 consecutive f -> hs
            for (int i = 0; i < 2; ++i) {
                int flocal = (fw * 2 + i) * 16 + l4 * 4;     // 4 consecutive f per lane
                float4 bv = *(const float4*)(b1 + (size_t)e * F + fbase + flocal);
                for (int j = 0; j < 2; ++j) {
                    int tok = (tw1 * 2 + j) * 16 + l15;
                    f32x4 hv = hacc[i][j];
                    f16x4 hp;
                    hp[0] = (_Float16)gelu_exact(hv[0] + bv.x);
                    hp[1] = (_Float16)gelu_exact(hv[1] + bv.y);
                    hp[2] = (_Float16)gelu_exact(hv[2] + bv.z);
                    hp[3] = (_Float16)gelu_exact(hv[3] + bv.w);
                    int idx = (tok * FC + flocal) ^ ((tok & 7) << 3);
                    *(f16x4*)&hs[idx] = hp;
                }
            }
            __syncthreads();

            // GEMM2: yT[h][tok] += W2t_rows · hs^T  (4x4 tiles/wave, K=FC)
            for (int ks = 0; ks < FC / 32; ++ks) {
                int kidx = ks * 32 + (l4 << 3);
                f16x8 av[4], bv2[4];
                for (int i = 0; i < 4; ++i) {
                    int hr = (hw * 4 + i) * 16 + l15;
                    av[i] = *(const f16x8*)&w2s[(hr * FC + kidx) ^ ((hr & 7) << 3)];
                }
                for (int j = 0; j < 4; ++j) {
                    int tok = (tw2 * 4 + j) * 16 + l15;
                    bv2[j] = *(const f16x8*)&hs[(tok * FC + kidx) ^ ((tok & 7) << 3)];
                }
                for (int i = 0; i < 4; ++i)
                    for (int j = 0; j < 4; ++j)
                        yacc[i][j] = __builtin_amdgcn_mfma_f32_16x16x32_f16(av[i], bv2[j], yacc[i][j], 0, 0, 0);
            }
        } // chunk loop

        // expert epilogue: mix += p[tok][e] * (y + b2[e][h])
        for (int j = 0; j < 4; ++j) {
            int tok = (tw2 * 4 + j) * 16 + l15;
            float p = probs[(size_t)(t0 + tok) * E + e];
            for (int i = 0; i < 4; ++i) {
                int hr = (hw * 4 + i) * 16 + l4 * 4;
                float4 b2v = *(const float4*)(b2 + (size_t)e * H + hr);
                mix[i][j][0] += p * (yacc[i][j][0] + b2v.x);
                mix[i][j][1] += p * (yacc[i][j][1] + b2v.y);
                mix[i][j][2] += p * (yacc[i][j][2] + b2v.z);
                mix[i][j][3] += p * (yacc[i][j][3] + b2v.w);
            }
        }
    } // expert loop

    // write mixed: lane holds 4 consecutive h per tile -> float4 stores
    for (int j = 0; j < 4; ++j) {
        int tok = t0 + (tw2 * 4 + j) * 16 + l15;
        for (int i = 0; i < 4; ++i) {
            int hr = (hw * 4 + i) * 16 + l4 * 4;
            *(f32x4*)(out + (size_t)tok * H + hr) = mix[i][j];
        }
    }
}

extern "C" void kernel_launch(void* const* d_in, const int* in_sizes, int n_in,
                              void* d_out, int out_size, void* d_ws, size_t ws_size,
                              hipStream_t stream) {
    const float* x  = (const float*)d_in[0];
    const float* Wg = (const float*)d_in[1];
    const float* bg = (const float*)d_in[2];
    const float* W1 = (const float*)d_in[3];
    const float* b1 = (const float*)d_in[4];
    const float* W2 = (const float*)d_in[5];
    const float* b2 = (const float*)d_in[6];
    float* out = (float*)d_out;

    _Float16* W1t = (_Float16*)d_ws;                       // [E][F][H] fp16, 2 MB
    _Float16* W2t = W1t + (size_t)E * F * H;               // [E][H][F] fp16, 2 MB
    float* probs  = (float*)(W2t + (size_t)E * H * F);     // [T][E] fp32, 1 MB

    dim3 tb(32, 8);
    transpose_cvt<<<dim3(F / 32, H / 32, E), tb, 0, stream>>>(W1, W1t, H, F);
    transpose_cvt<<<dim3(H / 32, F / 32, E), tb, 0, stream>>>(W2, W2t, F, H);
    gate_kernel<<<(T_TOK * E) / 256, 256, 0, stream>>>(x, Wg, bg, probs);
    moe_main<<<T_TOK / BM, 512, 0, stream>>>(x, W1t, b1, W2t, b2, probs, out);
}

// Round 2
// 239.594 us; speedup vs baseline: 1.6485x; 1.6485x over previous
//
#include <hip/hip_runtime.h>
#include <hip/hip_bf16.h>
#include <math.h>

#define H 256
#define F 512
#define E 8
#define T_TOK 32768
#define BM 128   // tokens per block
#define FC 64    // F-chunk size
#define NCH 64   // E * (F/FC) total chunk-stages

typedef float    f32x4 __attribute__((__ext_vector_type__(4)));
typedef _Float16 f16x8 __attribute__((__ext_vector_type__(8)));
typedef _Float16 f16x4 __attribute__((__ext_vector_type__(4)));

#define BAR_LG()  asm volatile("s_waitcnt lgkmcnt(0)\ns_barrier" ::: "memory")
#define BAR_ALL() asm volatile("s_waitcnt vmcnt(0) lgkmcnt(0)\ns_barrier" ::: "memory")

__device__ __forceinline__ void async_copy16(const void* g, void* l) {
    __builtin_amdgcn_global_load_lds((const __attribute__((address_space(1))) void*)g,
                                     (__attribute__((address_space(3))) void*)l, 16, 0, 0);
}

__device__ __forceinline__ float gelu_fast(float v) {
    // tanh-approx GELU: max |err| vs erf-GELU ~5e-4, hardware exp+rcp (~9 ops)
    float u = 0.7978845608028654f * v * (1.0f + 0.044715f * v * v);
    float ex = __expf(2.0f * u);
    float t = 1.0f - 2.0f * __builtin_amdgcn_rcpf(ex + 1.0f);
    return 0.5f * v * (1.0f + t);
}

// ---- transpose + convert: per expert, in fp32 [R][C] -> out fp16 [C][R]
__global__ void transpose_cvt(const float* __restrict__ in, _Float16* __restrict__ out,
                              int R, int C) {
    __shared__ float tile[32][33];
    int e = blockIdx.z;
    const float* inp = in + (size_t)e * R * C;
    _Float16* outp = out + (size_t)e * R * C;
    int c0 = blockIdx.x * 32, r0 = blockIdx.y * 32;
    int tx = threadIdx.x, ty = threadIdx.y; // 32 x 8
    for (int i = 0; i < 32; i += 8)
        tile[ty + i][tx] = inp[(size_t)(r0 + ty + i) * C + c0 + tx];
    __syncthreads();
    for (int i = 0; i < 32; i += 8)
        outp[(size_t)(c0 + ty + i) * R + r0 + tx] = (_Float16)tile[tx][ty + i];
}

// ---- gate: probs = softmax(x @ Wg + bg) over E; 8 threads per token
__global__ void gate_kernel(const float* __restrict__ x, const float* __restrict__ Wg,
                            const float* __restrict__ bg, float* __restrict__ probs) {
    int gid = blockIdx.x * blockDim.x + threadIdx.x;
    int t = gid >> 3, e = gid & 7;
    const float* xr = x + (size_t)t * H;
    float acc = 0.f;
    for (int k = 0; k < H; k += 4) {
        float4 xv = *(const float4*)(xr + k);
        acc += xv.x * Wg[(k + 0) * E + e] + xv.y * Wg[(k + 1) * E + e]
             + xv.z * Wg[(k + 2) * E + e] + xv.w * Wg[(k + 3) * E + e];
    }
    acc += bg[e];
    float m = acc;
    for (int s = 1; s < 8; s <<= 1) m = fmaxf(m, __shfl_xor(m, s, 8));
    float p = expf(acc - m);
    float sum = p;
    for (int s = 1; s < 8; s <<= 1) sum += __shfl_xor(sum, s, 8);
    probs[gid] = p / sum;
}

// stage chunk s's W1/W2 tiles into LDS via async global_load_lds (16B),
// linear LDS dest + pre-swizzled global source (swizzle: byte ^ ((row&7)<<4))
__device__ __forceinline__ void stage_chunk(const _Float16* W1t, const _Float16* W2t,
                                            int s, _Float16* w1d, _Float16* w2d,
                                            int wid, int lane) {
    int e = s >> 3, cc = s & 7, fbase = cc * FC;
    const char* W1c = (const char*)(W1t + (size_t)e * F * H + (size_t)fbase * H); // contiguous 32KB
    const char* W2c = (const char*)(W2t + (size_t)e * H * F) + fbase * 2;         // strided rows
#pragma unroll
    for (int q = 0; q < 4; ++q) {
        int seg = wid * 4 + q;             // 0..31, wave-uniform
        int o = seg * 1024 + lane * 16;    // linear byte offset in the 32KB tile
        // W1: rows of 512B (H fp16)
        int r1 = o >> 9;
        async_copy16(W1c + (o ^ ((r1 & 7) << 4)), (char*)w1d + seg * 1024);
        // W2: rows of 128B (FC fp16), global row stride F*2 = 1024B
        int r2 = o >> 7, cb = o & 127;
        async_copy16(W2c + r2 * 1024 + (cb ^ ((r2 & 7) << 4)), (char*)w2d + seg * 1024);
    }
}

// ---- main fused MoE FFN
__global__ __launch_bounds__(512, 2) void moe_main(
    const float* __restrict__ x, const _Float16* __restrict__ W1t,
    const float* __restrict__ b1, const _Float16* __restrict__ W2t,
    const float* __restrict__ b2, const float* __restrict__ probs,
    float* __restrict__ out) {

    __shared__ __align__(16) _Float16 w1s[2][FC * H];  // 2 x 32 KB
    __shared__ __align__(16) _Float16 w2s[2][H * FC];  // 2 x 32 KB
    __shared__ __align__(16) _Float16 hs[BM * FC];     // 16 KB

    int tid = threadIdx.x;
    int lane = tid & 63, wid = tid >> 6;
    int t0 = blockIdx.x * BM;
    int l15 = lane & 15, l4 = lane >> 4;

    // wave coords
    int fw = wid >> 2, tw1 = wid & 3;   // GEMM1: 2(f) x 4(tok), 2x2 16-tiles each
    int hw = wid >> 1, tw2 = wid & 1;   // GEMM2: 4(h) x 2(tok), 4x4 16-tiles each

    // x B-fragments in registers, loaded once, reused for all 64 chunk-stages.
    // frag[ks][j][e] = x[t0 + tw1*32 + j*16 + l15][ks*32 + l4*8 + e]  (fp16)
    f16x8 xf[8][2];
#pragma unroll
    for (int j = 0; j < 2; ++j) {
        const float* xr = x + (size_t)(t0 + tw1 * 32 + j * 16 + l15) * H + (l4 << 3);
#pragma unroll
        for (int ks = 0; ks < 8; ++ks) {
            const float4* gp = (const float4*)(xr + ks * 32);
            float4 v0 = gp[0], v1 = gp[1];
            f16x8 hv;
            hv[0] = (_Float16)v0.x; hv[1] = (_Float16)v0.y; hv[2] = (_Float16)v0.z; hv[3] = (_Float16)v0.w;
            hv[4] = (_Float16)v1.x; hv[5] = (_Float16)v1.y; hv[6] = (_Float16)v1.z; hv[7] = (_Float16)v1.w;
            xf[ks][j] = hv;
        }
    }

    // prologue: stage chunk 0 into buf 0
    stage_chunk(W1t, W2t, 0, w1s[0], w2s[0], wid, lane);
    BAR_ALL();

    f32x4 yacc[4][4];
#pragma unroll
    for (int i = 0; i < 4; ++i)
#pragma unroll
        for (int j = 0; j < 4; ++j) yacc[i][j] = (f32x4){0.f, 0.f, 0.f, 0.f};

    for (int e = 0; e < E; ++e) {
        // gate probs for this expert, tokens of this wave's GEMM1 tiles
        float pg0 = probs[(size_t)(t0 + tw1 * 32 + l15) * E + e];
        float pg1 = probs[(size_t)(t0 + tw1 * 32 + 16 + l15) * E + e];

        for (int c = 0; c < F / FC; ++c) {
            int s = e * 8 + c;
            int b = s & 1;
            int fbase = c * FC;
            const _Float16* w1p = w1s[b];
            const _Float16* w2p = w2s[b];

            // prefetch next chunk into the other buffer (in flight until BAR_ALL)
            if (s + 1 < NCH)
                stage_chunk(W1t, W2t, s + 1, w1s[b ^ 1], w2s[b ^ 1], wid, lane);

            // GEMM1: hT[f][tok] = W1chunk . x^T, K=H  (x from registers)
            f32x4 hacc[2][2];
            hacc[0][0] = hacc[0][1] = hacc[1][0] = hacc[1][1] = (f32x4){0.f, 0.f, 0.f, 0.f};
#pragma unroll
            for (int ks = 0; ks < 8; ++ks) {
                int kidx = ks * 32 + (l4 << 3);
                int fr0 = fw * 32 + l15, fr1 = fr0 + 16;
                f16x8 a0 = *(const f16x8*)&w1p[(fr0 * H + kidx) ^ ((fr0 & 7) << 3)];
                f16x8 a1 = *(const f16x8*)&w1p[(fr1 * H + kidx) ^ ((fr1 & 7) << 3)];
                hacc[0][0] = __builtin_amdgcn_mfma_f32_16x16x32_f16(a0, xf[ks][0], hacc[0][0], 0, 0, 0);
                hacc[0][1] = __builtin_amdgcn_mfma_f32_16x16x32_f16(a0, xf[ks][1], hacc[0][1], 0, 0, 0);
                hacc[1][0] = __builtin_amdgcn_mfma_f32_16x16x32_f16(a1, xf[ks][0], hacc[1][0], 0, 0, 0);
                hacc[1][1] = __builtin_amdgcn_mfma_f32_16x16x32_f16(a1, xf[ks][1], hacc[1][1], 0, 0, 0);
            }
            // epilogue: hs = p * gelu(h + b1)  (gate prob folded in pre-GEMM2)
#pragma unroll
            for (int i = 0; i < 2; ++i) {
                int flocal = (fw * 2 + i) * 16 + l4 * 4;
                float4 bv = *(const float4*)(b1 + (size_t)e * F + fbase + flocal);
#pragma unroll
                for (int j = 0; j < 2; ++j) {
                    int tokl = tw1 * 32 + j * 16 + l15;
                    float p = j ? pg1 : pg0;
                    f32x4 hv = hacc[i][j];
                    f16x4 hp;
                    hp[0] = (_Float16)(p * gelu_fast(hv[0] + bv.x));
                    hp[1] = (_Float16)(p * gelu_fast(hv[1] + bv.y));
                    hp[2] = (_Float16)(p * gelu_fast(hv[2] + bv.z));
                    hp[3] = (_Float16)(p * gelu_fast(hv[3] + bv.w));
                    int idx = (tokl * FC + flocal) ^ ((tokl & 7) << 3);
                    *(f16x4*)&hs[idx] = hp;
                }
            }
            BAR_LG();  // hs ready; prefetch stays in flight (no vmcnt drain)

            // GEMM2: y[h][tok] += W2chunk . hs^T, K=FC; accumulates across chunks AND experts
#pragma unroll
            for (int ks = 0; ks < FC / 32; ++ks) {
                int kidx = ks * 32 + (l4 << 3);
                f16x8 av[4], bv2[4];
#pragma unroll
                for (int i = 0; i < 4; ++i) {
                    int hr = hw * 64 + i * 16 + l15;
                    av[i] = *(const f16x8*)&w2p[(hr * FC + kidx) ^ ((hr & 7) << 3)];
                }
#pragma unroll
                for (int j = 0; j < 4; ++j) {
                    int tok = tw2 * 64 + j * 16 + l15;
                    bv2[j] = *(const f16x8*)&hs[(tok * FC + kidx) ^ ((tok & 7) << 3)];
                }
#pragma unroll
                for (int i = 0; i < 4; ++i)
#pragma unroll
                    for (int j = 0; j < 4; ++j)
                        yacc[i][j] = __builtin_amdgcn_mfma_f32_16x16x32_f16(av[i], bv2[j], yacc[i][j], 0, 0, 0);
            }
            BAR_ALL();  // GEMM2 reads done + next chunk's staging landed
        } // chunk loop
    } // expert loop

    // epilogue: out = yacc + sum_e p_e * b2_e ; write fp32
#pragma unroll
    for (int j = 0; j < 4; ++j) {
        int tok = t0 + tw2 * 64 + j * 16 + l15;
        for (int e = 0; e < 8; ++e) {
            float pe = probs[(size_t)tok * E + e];
#pragma unroll
            for (int i = 0; i < 4; ++i) {
                int h0 = hw * 64 + i * 16 + l4 * 4;
                float4 b2v = *(const float4*)(b2 + (size_t)e * H + h0);
                yacc[i][j][0] += pe * b2v.x;
                yacc[i][j][1] += pe * b2v.y;
                yacc[i][j][2] += pe * b2v.z;
                yacc[i][j][3] += pe * b2v.w;
            }
        }
#pragma unroll
        for (int i = 0; i < 4; ++i) {
            int h0 = hw * 64 + i * 16 + l4 * 4;
            *(f32x4*)(out + (size_t)tok * H + h0) = yacc[i][j];
        }
    }
}

extern "C" void kernel_launch(void* const* d_in, const int* in_sizes, int n_in,
                              void* d_out, int out_size, void* d_ws, size_t ws_size,
                              hipStream_t stream) {
    const float* x  = (const float*)d_in[0];
    const float* Wg = (const float*)d_in[1];
    const float* bg = (const float*)d_in[2];
    const float* W1 = (const float*)d_in[3];
    const float* b1 = (const float*)d_in[4];
    const float* W2 = (const float*)d_in[5];
    const float* b2 = (const float*)d_in[6];
    float* out = (float*)d_out;

    _Float16* W1t = (_Float16*)d_ws;                       // [E][F][H] fp16, 2 MB
    _Float16* W2t = W1t + (size_t)E * F * H;               // [E][H][F] fp16, 2 MB
    float* probs  = (float*)(W2t + (size_t)E * H * F);     // [T][E] fp32, 1 MB

    dim3 tb(32, 8);
    transpose_cvt<<<dim3(F / 32, H / 32, E), tb, 0, stream>>>(W1, W1t, H, F);
    transpose_cvt<<<dim3(H / 32, F / 32, E), tb, 0, stream>>>(W2, W2t, F, H);
    gate_kernel<<<(T_TOK * E) / 256, 256, 0, stream>>>(x, Wg, bg, probs);
    moe_main<<<T_TOK / BM, 512, 0, stream>>>(x, W1t, b1, W2t, b2, probs, out);
}